// Round 17
// baseline (125.937 us; speedup 1.0000x reference)
//
#include <hip/hip_runtime.h>
#include <stdint.h>

#define B_ 8
#define L_ 512
#define D_ 1024
#define H_ 16
#define HD_ 64
#define BH_ (B_*H_)      // 128
#define NR_ (B_*L_)      // 4096 rows
#define ALPHA_ 0.02f
#define PSTR 72          // padded LDS stride for per-lane-written P/E tiles

typedef unsigned int u32;
typedef unsigned short u16;
typedef __attribute__((ext_vector_type(8))) short bf16x8;
typedef __attribute__((ext_vector_type(4))) float f32x4;

#define MFMA16(a, b, c) __builtin_amdgcn_mfma_f32_16x16x32_bf16((a), (b), (c), 0, 0, 0)

__device__ __forceinline__ u32 f2bf_rne(float f) {
    u32 x = __float_as_uint(f);
    return (x + 0x7fffu + ((x >> 16) & 1u)) >> 16;
}
__device__ __forceinline__ float bf_lo(u32 u) { return __uint_as_float(u << 16); }
__device__ __forceinline__ float bf_hi(u32 u) { return __uint_as_float(u & 0xffff0000u); }

__device__ __forceinline__ void pack4_store(float4 v, u16* p) {
    uint2 u;
    u.x = f2bf_rne(v.x) | (f2bf_rne(v.y) << 16);
    u.y = f2bf_rne(v.z) | (f2bf_rne(v.w) << 16);
    *(uint2*)p = u;
}

// global->LDS DMA, 16B/lane; LDS dest = wave-uniform base + lane*16 (linear).
__device__ __forceinline__ void gl_lds16(const u16* g, u16* l) {
    auto gp = reinterpret_cast<const __attribute__((address_space(1))) void*>(
        reinterpret_cast<uintptr_t>(g));
    auto lp = reinterpret_cast<__attribute__((address_space(3))) void*>(
        reinterpret_cast<uintptr_t>(l));
    __builtin_amdgcn_global_load_lds(gp, lp, 16, 0, 0);
}

// XOR-swizzle (T2 / rule #21): linear LDS [rows][64 u16]; 16B-unit index within
// each row permuted by unit ^= (row & 7); staging pre-swizzles the per-lane
// GLOBAL source, reads apply the same XOR (involution => exact).
__device__ __forceinline__ void stage8_swz(const u16* g, size_t gpitch, u16* lds, int lane) {
    const int lrow = lane >> 3;              // 0..7 == row&7 (chunks 8-aligned)
    const int su = (lane & 7) ^ lrow;        // swizzled source 16B-unit
    gl_lds16(&g[(size_t)lrow * gpitch + su * 8], lds);
}

// T1 XCD-aware chunked block swizzle (m157; requires nwg % 8 == 0, bijective).
// HW assigns xcd = hw_linear_id % 8; remap so each XCD owns a CONTIGUOUS
// chunk of the logical block space -> data-sharing neighbors co-locate on L2.
__device__ __forceinline__ int xcd_swz(int orig, int nwg) {
    return (orig & 7) * (nwg >> 3) + (orig >> 3);
}

// ---------------------------------------------------------------------------
// prep: z<4 -> W[k][n] fp32 -> WTh[z][n][k] bf16 transposed; z==4 -> X cast.
// grid (16,16,5)
// ---------------------------------------------------------------------------
__global__ __launch_bounds__(256) void prep_kernel(
    const float* __restrict__ X, u16* __restrict__ Xh,
    const float* __restrict__ W0, const float* __restrict__ W1,
    const float* __restrict__ W2, const float* __restrict__ W3,
    u16* __restrict__ WTh)
{
    const int t = threadIdx.x;
    if (blockIdx.z == 4) {                  // cast X -> bf16 (16384 floats/block)
        const int cid = blockIdx.y * 16 + blockIdx.x;
        #pragma unroll
        for (int i = 0; i < 8; ++i) {
            const int n8 = cid * 2048 + i * 256 + t;   // index in 8-float units
            float4 a = ((const float4*)X)[(size_t)n8 * 2];
            float4 b = ((const float4*)X)[(size_t)n8 * 2 + 1];
            uint4 o;
            o.x = f2bf_rne(a.x) | (f2bf_rne(a.y) << 16);
            o.y = f2bf_rne(a.z) | (f2bf_rne(a.w) << 16);
            o.z = f2bf_rne(b.x) | (f2bf_rne(b.y) << 16);
            o.w = f2bf_rne(b.z) | (f2bf_rne(b.w) << 16);
            ((uint4*)Xh)[n8] = o;
        }
        return;
    }
    __shared__ float Ws[64][65];
    const int wsel = blockIdx.z;
    const float* W = (wsel == 0) ? W0 : (wsel == 1) ? W1 : (wsel == 2) ? W2 : W3;
    const int k0 = blockIdx.x * 64, n0 = blockIdx.y * 64;
    {
        const int r = t >> 2, c0 = (t & 3) << 4;
        #pragma unroll
        for (int i = 0; i < 4; ++i)
            *(float4*)&Ws[r][c0 + i * 4] = *(const float4*)&W[(size_t)(k0 + r) * 1024 + n0 + c0 + i * 4];
    }
    __syncthreads();
    {
        const int n = t >> 2, kc0 = (t & 3) << 4;
        size_t base = ((size_t)wsel << 20) + (size_t)(n0 + n) * 1024 + k0 + kc0;
        #pragma unroll
        for (int j = 0; j < 4; ++j) {
            float4 v;
            v.x = Ws[kc0 + j * 4 + 0][n]; v.y = Ws[kc0 + j * 4 + 1][n];
            v.z = Ws[kc0 + j * 4 + 2][n]; v.w = Ws[kc0 + j * 4 + 3][n];
            pack4_store(v, &WTh[base + j * 4]);
        }
    }
}

// ---------------------------------------------------------------------------
// MFMA GEMM, tile 64x128 (BK=64), 4 waves 2x2, per-wave 32x64 (acc[2][4]).
// Swizzled global_load_lds staging, linear LDS [rows][64].
// Grid (64, ny): logical block = XCD-swizzled linear id. QKV ny=24, out ny=8.
// TERMS=1: C = Ah@B^T'. TERMS=2: C = (Ah+Al)@B^T'.
// qkv_mode=1: fused QKV epilogue (Q bf16 / K bf16+Kn / V transposed VdT).
// qkv_mode=0: fp32 out + bias.
// ---------------------------------------------------------------------------
template<int TERMS>
__global__ __launch_bounds__(256) void gemm_mfma(
    const u16* __restrict__ Ah, const u16* __restrict__ Al,
    const u16* __restrict__ WTh,
    const float* __restrict__ b0, const float* __restrict__ b1, const float* __restrict__ b2,
    float* __restrict__ Cf, u16* __restrict__ Ch,
    u16* __restrict__ Kn, u16* __restrict__ VdT, int qkv_mode)
{
    __shared__ u16 Ash[64 * 64];
    __shared__ u16 Als[TERMS == 2 ? 64 * 64 : 8];
    __shared__ u16 Bsh[128 * 64];
    // T1 XCD swizzle (gridDim.x == 64; nwg divisible by 8)
    const int nwg = (int)(gridDim.x * gridDim.y);
    const int sw = xcd_swz((int)(blockIdx.y * gridDim.x + blockIdx.x), nwg);
    const int bm = sw & 63;
    const int yblk = sw >> 6;
    const int which = yblk >> 3;
    const int bn = yblk & 7;
    const float* bias = (which == 0) ? b0 : (which == 1) ? b1 : b2;
    const int t = threadIdx.x;
    const int w = t >> 6, lane = t & 63, l15 = lane & 15, g = lane >> 4;
    const int wr = w >> 1, wc = w & 1;
    const int row0 = bm * 64, col0 = bn * 128;
    const u16* Bg = WTh + ((size_t)which << 20);
    const int r7 = l15 & 7;

    f32x4 acc[2][4];
    #pragma unroll
    for (int i = 0; i < 2; ++i)
        #pragma unroll
        for (int j = 0; j < 4; ++j) acc[i][j] = (f32x4){0.f, 0.f, 0.f, 0.f};

    for (int kt = 0; kt < 1024; kt += 64) {
        __syncthreads();
        #pragma unroll
        for (int q = 0; q < 2; ++q) {               // A rows: wave w -> [w*16, w*16+16)
            const int rb = w * 16 + q * 8;
            stage8_swz(&Ah[(size_t)(row0 + rb) * 1024 + kt], 1024, &Ash[rb * 64], lane);
            if constexpr (TERMS == 2)
                stage8_swz(&Al[(size_t)(row0 + rb) * 1024 + kt], 1024, &Als[rb * 64], lane);
        }
        #pragma unroll
        for (int q = 0; q < 4; ++q) {               // B rows: wave w -> [w*32, w*32+32)
            const int rb = w * 32 + q * 8;
            stage8_swz(&Bg[(size_t)(col0 + rb) * 1024 + kt], 1024, &Bsh[rb * 64], lane);
        }
        __syncthreads();
        #pragma unroll
        for (int c = 0; c < 2; ++c) {
            const int uo = ((c * 4 + g) ^ r7) * 8;
            bf16x8 ah[2], al[2], bh[4];
            #pragma unroll
            for (int mf = 0; mf < 2; ++mf) {
                const int ro = (wr * 32 + mf * 16 + l15) * 64 + uo;
                ah[mf] = *(const bf16x8*)&Ash[ro];
                if constexpr (TERMS == 2) al[mf] = *(const bf16x8*)&Als[ro];
            }
            #pragma unroll
            for (int nf = 0; nf < 4; ++nf)
                bh[nf] = *(const bf16x8*)&Bsh[(wc * 64 + nf * 16 + l15) * 64 + uo];
            #pragma unroll
            for (int mf = 0; mf < 2; ++mf)
                #pragma unroll
                for (int nf = 0; nf < 4; ++nf) {
                    acc[mf][nf] = MFMA16(ah[mf], bh[nf], acc[mf][nf]);
                    if constexpr (TERMS == 2)
                        acc[mf][nf] = MFMA16(al[mf], bh[nf], acc[mf][nf]);
                }
        }
    }

    if (!qkv_mode) {
        #pragma unroll
        for (int mf = 0; mf < 2; ++mf)
            #pragma unroll
            for (int nf = 0; nf < 4; ++nf) {
                const int n = col0 + wc * 64 + nf * 16 + l15;
                const float bv = bias[n];
                #pragma unroll
                for (int r = 0; r < 4; ++r) {
                    const int m = row0 + wr * 32 + mf * 16 + g * 4 + r;
                    Cf[(size_t)m * 1024 + n] = acc[mf][nf][r] + bv;
                }
            }
        return;
    }
    if (which == 0) {               // Q: plain bf16
        #pragma unroll
        for (int mf = 0; mf < 2; ++mf)
            #pragma unroll
            for (int nf = 0; nf < 4; ++nf) {
                const int n = col0 + wc * 64 + nf * 16 + l15;
                const float bv = bias[n];
                #pragma unroll
                for (int r = 0; r < 4; ++r) {
                    const int m = row0 + wr * 32 + mf * 16 + g * 4 + r;
                    Ch[(size_t)m * 1024 + n] = (u16)f2bf_rne(acc[mf][nf][r] + bv);
                }
            }
    } else if (which == 1) {        // K: Kh + Kn (row-norm over the wave's head)
        #pragma unroll
        for (int mf = 0; mf < 2; ++mf) {
            float v[4][4];          // [nf][r]
            float sq[4] = {0.f, 0.f, 0.f, 0.f};
            #pragma unroll
            for (int nf = 0; nf < 4; ++nf) {
                const int n = col0 + wc * 64 + nf * 16 + l15;
                const float bv = bias[n];
                #pragma unroll
                for (int r = 0; r < 4; ++r) {
                    v[nf][r] = acc[mf][nf][r] + bv;
                    sq[r] += v[nf][r] * v[nf][r];
                }
            }
            #pragma unroll
            for (int r = 0; r < 4; ++r) {
                sq[r] += __shfl_xor(sq[r], 1);
                sq[r] += __shfl_xor(sq[r], 2);
                sq[r] += __shfl_xor(sq[r], 4);
                sq[r] += __shfl_xor(sq[r], 8);
            }
            float rn[4];
            #pragma unroll
            for (int r = 0; r < 4; ++r)
                rn[r] = 1.f / fmaxf(sqrtf(sq[r]), 1e-6f);
            #pragma unroll
            for (int nf = 0; nf < 4; ++nf) {
                const int n = col0 + wc * 64 + nf * 16 + l15;
                #pragma unroll
                for (int r = 0; r < 4; ++r) {
                    const int m = row0 + wr * 32 + mf * 16 + g * 4 + r;
                    Ch[((size_t)1 << 22) + (size_t)m * 1024 + n] = (u16)f2bf_rne(v[nf][r]);
                    Kn[(size_t)m * 1024 + n] = (u16)f2bf_rne(v[nf][r] * rn[r]);
                }
            }
        }
    } else {                        // V: transposed per-head store
        #pragma unroll
        for (int mf = 0; mf < 2; ++mf) {
            const int m0 = row0 + wr * 32 + mf * 16 + g * 4;
            const int bb = m0 >> 9, l0v = m0 & 511;
            #pragma unroll
            for (int nf = 0; nf < 4; ++nf) {
                const int n = col0 + wc * 64 + nf * 16 + l15;
                const float bv = bias[n];
                const int hh = n >> 6, dd = n & 63;
                const size_t idx = (((size_t)(bb * 16 + hh) * 64 + dd) * 512) + l0v;
                uint2 u;
                u.x = f2bf_rne(acc[mf][nf][0] + bv) | (f2bf_rne(acc[mf][nf][1] + bv) << 16);
                u.y = f2bf_rne(acc[mf][nf][2] + bv) | (f2bf_rne(acc[mf][nf][3] + bv) << 16);
                *(uint2*)&VdT[idx] = u;
            }
        }
    }
}

// ---------------------------------------------------------------------------
// Fused QGFD: WhT = bf16( (1-a) V^T + a * Dinv.(E @ V)^T ), RBLK=128 (2 sub-
// tiles of 64 rows share each staged Kn/V j-tile). grid (4 rtiles, 128 bh),
// XCD-swizzled so each XCD owns 16 contiguous heads (2MB < 4MB L2).
// E = exp(cos-sim/8) on the fly; scores in [-1/8,1/8] -> no running max.
// ---------------------------------------------------------------------------
__global__ __launch_bounds__(256) void qgfd_mfma(
    const u16* __restrict__ Kn_g, const u16* __restrict__ VdT,
    u16* __restrict__ WhT)
{
    __shared__ u16 Rs[128 * 64];           // Kn rows r0..r0+127 (B operand)
    __shared__ u16 Js[64 * 64];            // Kn rows jt.. (A operand)
    __shared__ u16 Vs[64 * 64];            // VdT tile [64 d][64 j]
    __shared__ u16 Eh[4][16 * PSTR];       // per-wave E relay (C->A layout)
    const int sw = xcd_swz((int)(blockIdx.y * 4 + blockIdx.x), 512);
    const int bh = sw >> 2, b = bh >> 4, h = bh & 15;
    const int r0 = (sw & 3) * 128;
    const int t = threadIdx.x;
    const int w = t >> 6, lane = t & 63, l15 = lane & 15, g = lane >> 4;
    const int r7 = l15 & 7;

    #pragma unroll
    for (int q = 0; q < 4; ++q) {
        const int rb = w * 32 + q * 8;
        stage8_swz(&Kn_g[((size_t)(b * 512 + r0 + rb)) * 1024 + h * 64], 1024,
                   &Rs[rb * 64], lane);
    }
    __syncthreads();
    bf16x8 rbf[2][2];
    #pragma unroll
    for (int rt = 0; rt < 2; ++rt) {
        rbf[rt][0] = *(const bf16x8*)&Rs[(rt * 64 + w * 16 + l15) * 64 + ((g ^ r7) * 8)];
        rbf[rt][1] = *(const bf16x8*)&Rs[(rt * 64 + w * 16 + l15) * 64 + (((4 + g) ^ r7) * 8)];
    }

    float rsum[2] = {0.f, 0.f};
    f32x4 O[2][4] = {{{0,0,0,0},{0,0,0,0},{0,0,0,0},{0,0,0,0}},
                     {{0,0,0,0},{0,0,0,0},{0,0,0,0},{0,0,0,0}}};

    for (int jt = 0; jt < 512; jt += 64) {
        __syncthreads();
        #pragma unroll
        for (int q = 0; q < 2; ++q) {
            const int rb = w * 16 + q * 8;
            stage8_swz(&Kn_g[((size_t)(b * 512 + jt + rb)) * 1024 + h * 64], 1024,
                       &Js[rb * 64], lane);
            stage8_swz(&VdT[((size_t)(bh * 64 + rb)) * 512 + jt], 512,
                       &Vs[rb * 64], lane);
        }
        __syncthreads();
        #pragma unroll
        for (int rt = 0; rt < 2; ++rt) {
            // E^T tiles: rows j, cols r (lane l15 = r-local)
            #pragma unroll
            for (int tk = 0; tk < 4; ++tk) {
                f32x4 a = {0.f, 0.f, 0.f, 0.f};
                #pragma unroll
                for (int c = 0; c < 2; ++c) {
                    bf16x8 ka = *(const bf16x8*)&Js[(tk * 16 + l15) * 64 + (((c * 4 + g) ^ r7) * 8)];
                    a = MFMA16(ka, rbf[rt][c], a);
                }
                const float e0 = __expf(a[0] * 0.125f);
                const float e1 = __expf(a[1] * 0.125f);
                const float e2 = __expf(a[2] * 0.125f);
                const float e3 = __expf(a[3] * 0.125f);
                rsum[rt] += e0 + e1 + e2 + e3;
                uint2 u;
                u.x = f2bf_rne(e0) | (f2bf_rne(e1) << 16);
                u.y = f2bf_rne(e2) | (f2bf_rne(e3) << 16);
                *(uint2*)&Eh[w][l15 * PSTR + tk * 16 + g * 4] = u;
            }
            // O += E_tile @ V_tile (Eh is wave-local; reused per rt)
            bf16x8 pah[2];
            pah[0] = *(const bf16x8*)&Eh[w][l15 * PSTR + 8 * g];
            pah[1] = *(const bf16x8*)&Eh[w][l15 * PSTR + 32 + 8 * g];
            #pragma unroll
            for (int td = 0; td < 4; ++td) {
                #pragma unroll
                for (int c = 0; c < 2; ++c) {
                    bf16x8 vb = *(const bf16x8*)&Vs[(td * 16 + l15) * 64 + (((c * 4 + g) ^ r7) * 8)];
                    O[rt][td] = MFMA16(pah[c], vb, O[rt][td]);
                }
            }
        }
    }
    #pragma unroll
    for (int rt = 0; rt < 2; ++rt) {
        float rs = rsum[rt];
        rs += __shfl_xor(rs, 16);
        rs += __shfl_xor(rs, 32);
        const float dinv = (1.0f - 1e-6f) / rs;
        float dv[4];
        #pragma unroll
        for (int r = 0; r < 4; ++r) dv[r] = __shfl(dinv, g * 4 + r) * ALPHA_;
        #pragma unroll
        for (int td = 0; td < 4; ++td) {
            const int d = td * 16 + l15;
            const size_t idx = ((size_t)bh * 64 + d) * 512 + r0 + rt * 64 + w * 16 + g * 4;
            uint2 vv = *(const uint2*)&VdT[idx];
            uint2 wu;
            wu.x = f2bf_rne((1.0f - ALPHA_) * bf_lo(vv.x) + dv[0] * O[rt][td][0])
                 | (f2bf_rne((1.0f - ALPHA_) * bf_hi(vv.x) + dv[1] * O[rt][td][1]) << 16);
            wu.y = f2bf_rne((1.0f - ALPHA_) * bf_lo(vv.y) + dv[2] * O[rt][td][2])
                 | (f2bf_rne((1.0f - ALPHA_) * bf_hi(vv.y) + dv[3] * O[rt][td][3]) << 16);
            *(uint2*)&WhT[idx] = wu;
        }
    }
}

// ---------------------------------------------------------------------------
// attn = softmax(QK^T/8) @ W, flash-style, QBLK=128 (2 q-subtiles share each
// staged K/W tile). QK x1, PV x1. grid (4 qtiles, 128 bh), XCD-swizzled.
// ---------------------------------------------------------------------------
__global__ __launch_bounds__(256) void attn_mfma(
    const u16* __restrict__ Qh_g, const u16* __restrict__ Kh_g,
    const u16* __restrict__ Wh_g,
    u16* __restrict__ attnh, u16* __restrict__ attnl)
{
    __shared__ u16 Qs[128 * 64];
    __shared__ u16 Ks[64 * 64];
    __shared__ u16 Wsh[64 * 64];
    __shared__ u16 Ph[4][16 * PSTR];
    const int sw = xcd_swz((int)(blockIdx.y * 4 + blockIdx.x), 512);
    const int bh = sw >> 2, b = bh >> 4, h = bh & 15;
    const int q0 = (sw & 3) * 128;
    const int t = threadIdx.x;
    const int w = t >> 6, lane = t & 63, l15 = lane & 15, g = lane >> 4;
    const int r7 = l15 & 7;

    #pragma unroll
    for (int q = 0; q < 4; ++q) {
        const int rb = w * 32 + q * 8;
        stage8_swz(&Qh_g[((size_t)(b * 512 + q0 + rb)) * 1024 + h * 64], 1024,
                   &Qs[rb * 64], lane);
    }
    __syncthreads();
    bf16x8 qbh[2][2];
    #pragma unroll
    for (int qt = 0; qt < 2; ++qt) {
        qbh[qt][0] = *(const bf16x8*)&Qs[(qt * 64 + w * 16 + l15) * 64 + ((g ^ r7) * 8)];
        qbh[qt][1] = *(const bf16x8*)&Qs[(qt * 64 + w * 16 + l15) * 64 + (((4 + g) ^ r7) * 8)];
    }

    float m_run[2] = {-1e30f, -1e30f}, l_run[2] = {0.f, 0.f};
    f32x4 O[2][4] = {{{0,0,0,0},{0,0,0,0},{0,0,0,0},{0,0,0,0}},
                     {{0,0,0,0},{0,0,0,0},{0,0,0,0},{0,0,0,0}}};

    for (int kt = 0; kt < 512; kt += 64) {
        __syncthreads();
        #pragma unroll
        for (int q = 0; q < 2; ++q) {
            const int rb = w * 16 + q * 8;
            stage8_swz(&Kh_g[((size_t)(b * 512 + kt + rb)) * 1024 + h * 64], 1024,
                       &Ks[rb * 64], lane);
            stage8_swz(&Wh_g[((size_t)(bh * 64 + rb)) * 512 + kt], 512,
                       &Wsh[rb * 64], lane);
        }
        __syncthreads();
        #pragma unroll
        for (int qt = 0; qt < 2; ++qt) {
            f32x4 st[4];
            #pragma unroll
            for (int tk = 0; tk < 4; ++tk) {
                f32x4 a = {0.f, 0.f, 0.f, 0.f};
                #pragma unroll
                for (int c = 0; c < 2; ++c) {
                    bf16x8 kah = *(const bf16x8*)&Ks[(tk * 16 + l15) * 64 + (((c * 4 + g) ^ r7) * 8)];
                    a = MFMA16(kah, qbh[qt][c], a);
                }
                st[tk] = a;
            }
            float mt = st[0][0];
            #pragma unroll
            for (int tk = 0; tk < 4; ++tk)
                #pragma unroll
                for (int r = 0; r < 4; ++r) mt = fmaxf(mt, st[tk][r]);
            mt = fmaxf(mt, __shfl_xor(mt, 16));
            mt = fmaxf(mt, __shfl_xor(mt, 32));
            const float m_new = fmaxf(m_run[qt], mt);
            const float scale = __expf((m_run[qt] - m_new) * 0.125f);
            float rsum = 0.f;
            #pragma unroll
            for (int tk = 0; tk < 4; ++tk) {
                float p0_ = __expf((st[tk][0] - m_new) * 0.125f);
                float p1_ = __expf((st[tk][1] - m_new) * 0.125f);
                float p2_ = __expf((st[tk][2] - m_new) * 0.125f);
                float p3_ = __expf((st[tk][3] - m_new) * 0.125f);
                rsum += p0_ + p1_ + p2_ + p3_;
                uint2 hw;
                hw.x = f2bf_rne(p0_) | (f2bf_rne(p1_) << 16);
                hw.y = f2bf_rne(p2_) | (f2bf_rne(p3_) << 16);
                *(uint2*)&Ph[w][l15 * PSTR + tk * 16 + g * 4] = hw;
            }
            rsum += __shfl_xor(rsum, 16);
            rsum += __shfl_xor(rsum, 32);
            l_run[qt] = l_run[qt] * scale + rsum;
            m_run[qt] = m_new;
            float sc[4];
            #pragma unroll
            for (int r = 0; r < 4; ++r) sc[r] = __shfl(scale, g * 4 + r);
            #pragma unroll
            for (int td = 0; td < 4; ++td)
                #pragma unroll
                for (int r = 0; r < 4; ++r) O[qt][td][r] *= sc[r];
            bf16x8 pah[2];
            pah[0] = *(const bf16x8*)&Ph[w][l15 * PSTR + 8 * g];
            pah[1] = *(const bf16x8*)&Ph[w][l15 * PSTR + 32 + 8 * g];
            #pragma unroll
            for (int td = 0; td < 4; ++td) {
                #pragma unroll
                for (int c = 0; c < 2; ++c) {
                    bf16x8 wbh = *(const bf16x8*)&Wsh[(td * 16 + l15) * 64 + (((c * 4 + g) ^ r7) * 8)];
                    O[qt][td] = MFMA16(pah[c], wbh, O[qt][td]);
                }
            }
        }
    }
    #pragma unroll
    for (int qt = 0; qt < 2; ++qt) {
        const float linv = 1.f / l_run[qt];
        float li[4];
        #pragma unroll
        for (int r = 0; r < 4; ++r) li[r] = __shfl(linv, g * 4 + r);
        #pragma unroll
        for (int td = 0; td < 4; ++td)
            #pragma unroll
            for (int r = 0; r < 4; ++r) {
                const float v = O[qt][td][r] * li[r];
                const size_t idx = ((size_t)(b * 512 + q0 + qt * 64 + w * 16 + g * 4 + r)) * 1024
                                 + h * 64 + td * 16 + l15;
                const u32 hh = f2bf_rne(v);
                attnh[idx] = (u16)hh;
                attnl[idx] = (u16)f2bf_rne(v - bf_lo(hh));
            }
    }
}

// ---------------------------------------------------------------------------
extern "C" void kernel_launch(void* const* d_in, const int* in_sizes, int n_in,
                              void* d_out, int out_size, void* d_ws, size_t ws_size,
                              hipStream_t stream) {
    const float* X  = (const float*)d_in[0];
    const float* Wq = (const float*)d_in[1];
    const float* bq = (const float*)d_in[2];
    const float* Wk = (const float*)d_in[3];
    const float* bk = (const float*)d_in[4];
    const float* Wv = (const float*)d_in[5];
    const float* bv = (const float*)d_in[6];
    const float* Wo = (const float*)d_in[7];
    const float* bo = (const float*)d_in[8];
    float* out = (float*)d_out;

    char* ws = (char*)d_ws;
    size_t off = 0;
    auto alloc = [&](size_t bytes) -> void* {
        void* p = ws + off;
        off += (bytes + 255) & ~(size_t)255;
        return p;
    };
    const size_t NE = (size_t)NR_ * D_;               // 4,194,304
    const size_t HE = (size_t)BH_ * 64 * 512;         // 4,194,304
    u16*   Xh    = (u16*)alloc(NE * 2);
    u16*   WTh   = (u16*)alloc((size_t)4 * 1024 * 1024 * 2);
    u16*   QKh   = (u16*)alloc(2 * NE * 2);           // [Q|K][4096][1024]
    u16*   Kn    = (u16*)alloc(NE * 2);
    u16*   VdT   = (u16*)alloc(HE * 2);
    u16*   WhT   = (u16*)alloc(HE * 2);
    u16*   attnh = (u16*)alloc(NE * 2);
    u16*   attnl = (u16*)alloc(NE * 2);

    const u16* Qh_g = QKh;
    const u16* Kh_g = QKh + NE;

    dim3 blk(256);
    prep_kernel<<<dim3(16, 16, 5), blk, 0, stream>>>(X, Xh, Wq, Wk, Wv, Wo, WTh);
    gemm_mfma<1><<<dim3(64, 24), blk, 0, stream>>>(Xh, nullptr, WTh, bq, bk, bv,
                                                   nullptr, QKh, Kn, VdT, 1);
    qgfd_mfma<<<dim3(4, BH_), blk, 0, stream>>>(Kn, VdT, WhT);
    attn_mfma<<<dim3(4, BH_), blk, 0, stream>>>(Qh_g, Kh_g, WhT, attnh, attnl);
    gemm_mfma<2><<<dim3(64, 8), blk, 0, stream>>>(attnh, attnl,
                                                  WTh + ((size_t)3 << 20),
                                                  bo, bo, bo, out, nullptr,
                                                  nullptr, nullptr, 0);
}

// Round 18
// 119.688 us; speedup vs baseline: 1.0522x; 1.0522x over previous
//
#include <hip/hip_runtime.h>
#include <stdint.h>

#define B_ 8
#define L_ 512
#define D_ 1024
#define H_ 16
#define HD_ 64
#define BH_ (B_*H_)      // 128
#define NR_ (B_*L_)      // 4096 rows
#define ALPHA_ 0.02f
#define PSTR 72          // padded LDS stride for per-lane-written P/E tiles

typedef unsigned int u32;
typedef unsigned short u16;
typedef __attribute__((ext_vector_type(8))) short bf16x8;
typedef __attribute__((ext_vector_type(4))) float f32x4;

#define MFMA16(a, b, c) __builtin_amdgcn_mfma_f32_16x16x32_bf16((a), (b), (c), 0, 0, 0)

__device__ __forceinline__ u32 f2bf_rne(float f) {
    u32 x = __float_as_uint(f);
    return (x + 0x7fffu + ((x >> 16) & 1u)) >> 16;
}
__device__ __forceinline__ float bf_lo(u32 u) { return __uint_as_float(u << 16); }
__device__ __forceinline__ float bf_hi(u32 u) { return __uint_as_float(u & 0xffff0000u); }

__device__ __forceinline__ void pack4_store(float4 v, u16* p) {
    uint2 u;
    u.x = f2bf_rne(v.x) | (f2bf_rne(v.y) << 16);
    u.y = f2bf_rne(v.z) | (f2bf_rne(v.w) << 16);
    *(uint2*)p = u;
}

// global->LDS DMA, 16B/lane; LDS dest = wave-uniform base + lane*16 (linear).
__device__ __forceinline__ void gl_lds16(const u16* g, u16* l) {
    auto gp = reinterpret_cast<const __attribute__((address_space(1))) void*>(
        reinterpret_cast<uintptr_t>(g));
    auto lp = reinterpret_cast<__attribute__((address_space(3))) void*>(
        reinterpret_cast<uintptr_t>(l));
    __builtin_amdgcn_global_load_lds(gp, lp, 16, 0, 0);
}

// XOR-swizzle (T2 / rule #21): linear LDS [rows][64 u16]; 16B-unit index within
// each row permuted by unit ^= (row & 7); staging pre-swizzles the per-lane
// GLOBAL source, reads apply the same XOR (involution => exact).
__device__ __forceinline__ void stage8_swz(const u16* g, size_t gpitch, u16* lds, int lane) {
    const int lrow = lane >> 3;              // 0..7 == row&7 (chunks 8-aligned)
    const int su = (lane & 7) ^ lrow;        // swizzled source 16B-unit
    gl_lds16(&g[(size_t)lrow * gpitch + su * 8], lds);
}

// ---------------------------------------------------------------------------
// prep: z<4 -> W[k][n] fp32 -> WTh[z][n][k] bf16 transposed; z==4 -> X cast.
// grid (16,16,5)
// ---------------------------------------------------------------------------
__global__ __launch_bounds__(256) void prep_kernel(
    const float* __restrict__ X, u16* __restrict__ Xh,
    const float* __restrict__ W0, const float* __restrict__ W1,
    const float* __restrict__ W2, const float* __restrict__ W3,
    u16* __restrict__ WTh)
{
    const int t = threadIdx.x;
    if (blockIdx.z == 4) {                  // cast X -> bf16 (16384 floats/block)
        const int cid = blockIdx.y * 16 + blockIdx.x;
        #pragma unroll
        for (int i = 0; i < 8; ++i) {
            const int n8 = cid * 2048 + i * 256 + t;   // index in 8-float units
            float4 a = ((const float4*)X)[(size_t)n8 * 2];
            float4 b = ((const float4*)X)[(size_t)n8 * 2 + 1];
            uint4 o;
            o.x = f2bf_rne(a.x) | (f2bf_rne(a.y) << 16);
            o.y = f2bf_rne(a.z) | (f2bf_rne(a.w) << 16);
            o.z = f2bf_rne(b.x) | (f2bf_rne(b.y) << 16);
            o.w = f2bf_rne(b.z) | (f2bf_rne(b.w) << 16);
            ((uint4*)Xh)[n8] = o;
        }
        return;
    }
    __shared__ float Ws[64][65];
    const int wsel = blockIdx.z;
    const float* W = (wsel == 0) ? W0 : (wsel == 1) ? W1 : (wsel == 2) ? W2 : W3;
    const int k0 = blockIdx.x * 64, n0 = blockIdx.y * 64;
    {
        const int r = t >> 2, c0 = (t & 3) << 4;
        #pragma unroll
        for (int i = 0; i < 4; ++i)
            *(float4*)&Ws[r][c0 + i * 4] = *(const float4*)&W[(size_t)(k0 + r) * 1024 + n0 + c0 + i * 4];
    }
    __syncthreads();
    {
        const int n = t >> 2, kc0 = (t & 3) << 4;
        size_t base = ((size_t)wsel << 20) + (size_t)(n0 + n) * 1024 + k0 + kc0;
        #pragma unroll
        for (int j = 0; j < 4; ++j) {
            float4 v;
            v.x = Ws[kc0 + j * 4 + 0][n]; v.y = Ws[kc0 + j * 4 + 1][n];
            v.z = Ws[kc0 + j * 4 + 2][n]; v.w = Ws[kc0 + j * 4 + 3][n];
            pack4_store(v, &WTh[base + j * 4]);
        }
    }
}

// ---------------------------------------------------------------------------
// MFMA GEMM, tile 64x128 (BK=64), 4 waves 2x2, per-wave 32x64 (acc[2][4]).
// Swizzled global_load_lds staging, linear LDS [rows][64].
// Grid: (M/64, nw*8) where bn = y&7 over N/128. QKV 1536 blocks (6/CU),
// out-proj 512 (2/CU).
// TERMS=1: C = Ah@B^T'. TERMS=2: C = (Ah+Al)@B^T'.
// qkv_mode=1: fused QKV epilogue (Q bf16 / K bf16+Kn / V transposed VdT).
// qkv_mode=0: fp32 out + bias.
// ---------------------------------------------------------------------------
template<int TERMS>
__global__ __launch_bounds__(256) void gemm_mfma(
    const u16* __restrict__ Ah, const u16* __restrict__ Al,
    const u16* __restrict__ WTh,
    const float* __restrict__ b0, const float* __restrict__ b1, const float* __restrict__ b2,
    float* __restrict__ Cf, u16* __restrict__ Ch,
    u16* __restrict__ Kn, u16* __restrict__ VdT, int qkv_mode)
{
    __shared__ u16 Ash[64 * 64];
    __shared__ u16 Als[TERMS == 2 ? 64 * 64 : 8];
    __shared__ u16 Bsh[128 * 64];
    const int bm = blockIdx.x;
    const int which = blockIdx.y >> 3;
    const int bn = blockIdx.y & 7;
    const float* bias = (which == 0) ? b0 : (which == 1) ? b1 : b2;
    const int t = threadIdx.x;
    const int w = t >> 6, lane = t & 63, l15 = lane & 15, g = lane >> 4;
    const int wr = w >> 1, wc = w & 1;
    const int row0 = bm * 64, col0 = bn * 128;
    const u16* Bg = WTh + ((size_t)which << 20);
    const int r7 = l15 & 7;

    f32x4 acc[2][4];
    #pragma unroll
    for (int i = 0; i < 2; ++i)
        #pragma unroll
        for (int j = 0; j < 4; ++j) acc[i][j] = (f32x4){0.f, 0.f, 0.f, 0.f};

    for (int kt = 0; kt < 1024; kt += 64) {
        __syncthreads();
        #pragma unroll
        for (int q = 0; q < 2; ++q) {               // A rows: wave w -> [w*16, w*16+16)
            const int rb = w * 16 + q * 8;
            stage8_swz(&Ah[(size_t)(row0 + rb) * 1024 + kt], 1024, &Ash[rb * 64], lane);
            if constexpr (TERMS == 2)
                stage8_swz(&Al[(size_t)(row0 + rb) * 1024 + kt], 1024, &Als[rb * 64], lane);
        }
        #pragma unroll
        for (int q = 0; q < 4; ++q) {               // B rows: wave w -> [w*32, w*32+32)
            const int rb = w * 32 + q * 8;
            stage8_swz(&Bg[(size_t)(col0 + rb) * 1024 + kt], 1024, &Bsh[rb * 64], lane);
        }
        __syncthreads();
        #pragma unroll
        for (int c = 0; c < 2; ++c) {
            const int uo = ((c * 4 + g) ^ r7) * 8;
            bf16x8 ah[2], al[2], bh[4];
            #pragma unroll
            for (int mf = 0; mf < 2; ++mf) {
                const int ro = (wr * 32 + mf * 16 + l15) * 64 + uo;
                ah[mf] = *(const bf16x8*)&Ash[ro];
                if constexpr (TERMS == 2) al[mf] = *(const bf16x8*)&Als[ro];
            }
            #pragma unroll
            for (int nf = 0; nf < 4; ++nf)
                bh[nf] = *(const bf16x8*)&Bsh[(wc * 64 + nf * 16 + l15) * 64 + uo];
            #pragma unroll
            for (int mf = 0; mf < 2; ++mf)
                #pragma unroll
                for (int nf = 0; nf < 4; ++nf) {
                    acc[mf][nf] = MFMA16(ah[mf], bh[nf], acc[mf][nf]);
                    if constexpr (TERMS == 2)
                        acc[mf][nf] = MFMA16(al[mf], bh[nf], acc[mf][nf]);
                }
        }
    }

    if (!qkv_mode) {
        #pragma unroll
        for (int mf = 0; mf < 2; ++mf)
            #pragma unroll
            for (int nf = 0; nf < 4; ++nf) {
                const int n = col0 + wc * 64 + nf * 16 + l15;
                const float bv = bias[n];
                #pragma unroll
                for (int r = 0; r < 4; ++r) {
                    const int m = row0 + wr * 32 + mf * 16 + g * 4 + r;
                    Cf[(size_t)m * 1024 + n] = acc[mf][nf][r] + bv;
                }
            }
        return;
    }
    if (which == 0) {               // Q: plain bf16
        #pragma unroll
        for (int mf = 0; mf < 2; ++mf)
            #pragma unroll
            for (int nf = 0; nf < 4; ++nf) {
                const int n = col0 + wc * 64 + nf * 16 + l15;
                const float bv = bias[n];
                #pragma unroll
                for (int r = 0; r < 4; ++r) {
                    const int m = row0 + wr * 32 + mf * 16 + g * 4 + r;
                    Ch[(size_t)m * 1024 + n] = (u16)f2bf_rne(acc[mf][nf][r] + bv);
                }
            }
    } else if (which == 1) {        // K: Kh + Kn (row-norm over the wave's head)
        #pragma unroll
        for (int mf = 0; mf < 2; ++mf) {
            float v[4][4];          // [nf][r]
            float sq[4] = {0.f, 0.f, 0.f, 0.f};
            #pragma unroll
            for (int nf = 0; nf < 4; ++nf) {
                const int n = col0 + wc * 64 + nf * 16 + l15;
                const float bv = bias[n];
                #pragma unroll
                for (int r = 0; r < 4; ++r) {
                    v[nf][r] = acc[mf][nf][r] + bv;
                    sq[r] += v[nf][r] * v[nf][r];
                }
            }
            #pragma unroll
            for (int r = 0; r < 4; ++r) {
                sq[r] += __shfl_xor(sq[r], 1);
                sq[r] += __shfl_xor(sq[r], 2);
                sq[r] += __shfl_xor(sq[r], 4);
                sq[r] += __shfl_xor(sq[r], 8);
            }
            float rn[4];
            #pragma unroll
            for (int r = 0; r < 4; ++r)
                rn[r] = 1.f / fmaxf(sqrtf(sq[r]), 1e-6f);
            #pragma unroll
            for (int nf = 0; nf < 4; ++nf) {
                const int n = col0 + wc * 64 + nf * 16 + l15;
                #pragma unroll
                for (int r = 0; r < 4; ++r) {
                    const int m = row0 + wr * 32 + mf * 16 + g * 4 + r;
                    Ch[((size_t)1 << 22) + (size_t)m * 1024 + n] = (u16)f2bf_rne(v[nf][r]);
                    Kn[(size_t)m * 1024 + n] = (u16)f2bf_rne(v[nf][r] * rn[r]);
                }
            }
        }
    } else {                        // V: transposed per-head store
        #pragma unroll
        for (int mf = 0; mf < 2; ++mf) {
            const int m0 = row0 + wr * 32 + mf * 16 + g * 4;
            const int bb = m0 >> 9, l0v = m0 & 511;
            #pragma unroll
            for (int nf = 0; nf < 4; ++nf) {
                const int n = col0 + wc * 64 + nf * 16 + l15;
                const float bv = bias[n];
                const int hh = n >> 6, dd = n & 63;
                const size_t idx = (((size_t)(bb * 16 + hh) * 64 + dd) * 512) + l0v;
                uint2 u;
                u.x = f2bf_rne(acc[mf][nf][0] + bv) | (f2bf_rne(acc[mf][nf][1] + bv) << 16);
                u.y = f2bf_rne(acc[mf][nf][2] + bv) | (f2bf_rne(acc[mf][nf][3] + bv) << 16);
                *(uint2*)&VdT[idx] = u;
            }
        }
    }
}

// ---------------------------------------------------------------------------
// Fused QGFD: WhT = bf16( (1-a) V^T + a * Dinv.(E @ V)^T ), RBLK=128 (2 sub-
// tiles of 64 rows share each staged Kn/V j-tile). grid (4 rtiles, 128 bh).
// E = exp(cos-sim/8) on the fly; scores in [-1/8,1/8] -> no running max.
// ---------------------------------------------------------------------------
__global__ __launch_bounds__(256) void qgfd_mfma(
    const u16* __restrict__ Kn_g, const u16* __restrict__ VdT,
    u16* __restrict__ WhT)
{
    __shared__ u16 Rs[128 * 64];           // Kn rows r0..r0+127 (B operand)
    __shared__ u16 Js[64 * 64];            // Kn rows jt.. (A operand)
    __shared__ u16 Vs[64 * 64];            // VdT tile [64 d][64 j]
    __shared__ u16 Eh[4][16 * PSTR];       // per-wave E relay (C->A layout)
    const int bh = blockIdx.y, b = bh >> 4, h = bh & 15;
    const int r0 = blockIdx.x * 128;
    const int t = threadIdx.x;
    const int w = t >> 6, lane = t & 63, l15 = lane & 15, g = lane >> 4;
    const int r7 = l15 & 7;

    #pragma unroll
    for (int q = 0; q < 4; ++q) {
        const int rb = w * 32 + q * 8;
        stage8_swz(&Kn_g[((size_t)(b * 512 + r0 + rb)) * 1024 + h * 64], 1024,
                   &Rs[rb * 64], lane);
    }
    __syncthreads();
    bf16x8 rbf[2][2];
    #pragma unroll
    for (int rt = 0; rt < 2; ++rt) {
        rbf[rt][0] = *(const bf16x8*)&Rs[(rt * 64 + w * 16 + l15) * 64 + ((g ^ r7) * 8)];
        rbf[rt][1] = *(const bf16x8*)&Rs[(rt * 64 + w * 16 + l15) * 64 + (((4 + g) ^ r7) * 8)];
    }

    float rsum[2] = {0.f, 0.f};
    f32x4 O[2][4] = {{{0,0,0,0},{0,0,0,0},{0,0,0,0},{0,0,0,0}},
                     {{0,0,0,0},{0,0,0,0},{0,0,0,0},{0,0,0,0}}};

    for (int jt = 0; jt < 512; jt += 64) {
        __syncthreads();
        #pragma unroll
        for (int q = 0; q < 2; ++q) {
            const int rb = w * 16 + q * 8;
            stage8_swz(&Kn_g[((size_t)(b * 512 + jt + rb)) * 1024 + h * 64], 1024,
                       &Js[rb * 64], lane);
            stage8_swz(&VdT[((size_t)(bh * 64 + rb)) * 512 + jt], 512,
                       &Vs[rb * 64], lane);
        }
        __syncthreads();
        #pragma unroll
        for (int rt = 0; rt < 2; ++rt) {
            // E^T tiles: rows j, cols r (lane l15 = r-local)
            #pragma unroll
            for (int tk = 0; tk < 4; ++tk) {
                f32x4 a = {0.f, 0.f, 0.f, 0.f};
                #pragma unroll
                for (int c = 0; c < 2; ++c) {
                    bf16x8 ka = *(const bf16x8*)&Js[(tk * 16 + l15) * 64 + (((c * 4 + g) ^ r7) * 8)];
                    a = MFMA16(ka, rbf[rt][c], a);
                }
                const float e0 = __expf(a[0] * 0.125f);
                const float e1 = __expf(a[1] * 0.125f);
                const float e2 = __expf(a[2] * 0.125f);
                const float e3 = __expf(a[3] * 0.125f);
                rsum[rt] += e0 + e1 + e2 + e3;
                uint2 u;
                u.x = f2bf_rne(e0) | (f2bf_rne(e1) << 16);
                u.y = f2bf_rne(e2) | (f2bf_rne(e3) << 16);
                *(uint2*)&Eh[w][l15 * PSTR + tk * 16 + g * 4] = u;
            }
            // O += E_tile @ V_tile (Eh is wave-local; reused per rt)
            bf16x8 pah[2];
            pah[0] = *(const bf16x8*)&Eh[w][l15 * PSTR + 8 * g];
            pah[1] = *(const bf16x8*)&Eh[w][l15 * PSTR + 32 + 8 * g];
            #pragma unroll
            for (int td = 0; td < 4; ++td) {
                #pragma unroll
                for (int c = 0; c < 2; ++c) {
                    bf16x8 vb = *(const bf16x8*)&Vs[(td * 16 + l15) * 64 + (((c * 4 + g) ^ r7) * 8)];
                    O[rt][td] = MFMA16(pah[c], vb, O[rt][td]);
                }
            }
        }
    }
    #pragma unroll
    for (int rt = 0; rt < 2; ++rt) {
        float rs = rsum[rt];
        rs += __shfl_xor(rs, 16);
        rs += __shfl_xor(rs, 32);
        const float dinv = (1.0f - 1e-6f) / rs;
        float dv[4];
        #pragma unroll
        for (int r = 0; r < 4; ++r) dv[r] = __shfl(dinv, g * 4 + r) * ALPHA_;
        #pragma unroll
        for (int td = 0; td < 4; ++td) {
            const int d = td * 16 + l15;
            const size_t idx = ((size_t)bh * 64 + d) * 512 + r0 + rt * 64 + w * 16 + g * 4;
            uint2 vv = *(const uint2*)&VdT[idx];
            uint2 wu;
            wu.x = f2bf_rne((1.0f - ALPHA_) * bf_lo(vv.x) + dv[0] * O[rt][td][0])
                 | (f2bf_rne((1.0f - ALPHA_) * bf_hi(vv.x) + dv[1] * O[rt][td][1]) << 16);
            wu.y = f2bf_rne((1.0f - ALPHA_) * bf_lo(vv.y) + dv[2] * O[rt][td][2])
                 | (f2bf_rne((1.0f - ALPHA_) * bf_hi(vv.y) + dv[3] * O[rt][td][3]) << 16);
            *(uint2*)&WhT[idx] = wu;
        }
    }
}

// ---------------------------------------------------------------------------
// attn = softmax(QK^T/8) @ W, flash-style, QBLK=128 (2 q-subtiles share each
// staged K/W tile). QK x1, PV x1. grid (4 qtiles, 128 bh).
// ---------------------------------------------------------------------------
__global__ __launch_bounds__(256) void attn_mfma(
    const u16* __restrict__ Qh_g, const u16* __restrict__ Kh_g,
    const u16* __restrict__ Wh_g,
    u16* __restrict__ attnh, u16* __restrict__ attnl)
{
    __shared__ u16 Qs[128 * 64];
    __shared__ u16 Ks[64 * 64];
    __shared__ u16 Wsh[64 * 64];
    __shared__ u16 Ph[4][16 * PSTR];
    const int bh = blockIdx.y, b = bh >> 4, h = bh & 15;
    const int q0 = blockIdx.x * 128;
    const int t = threadIdx.x;
    const int w = t >> 6, lane = t & 63, l15 = lane & 15, g = lane >> 4;
    const int r7 = l15 & 7;

    #pragma unroll
    for (int q = 0; q < 4; ++q) {
        const int rb = w * 32 + q * 8;
        stage8_swz(&Qh_g[((size_t)(b * 512 + q0 + rb)) * 1024 + h * 64], 1024,
                   &Qs[rb * 64], lane);
    }
    __syncthreads();
    bf16x8 qbh[2][2];
    #pragma unroll
    for (int qt = 0; qt < 2; ++qt) {
        qbh[qt][0] = *(const bf16x8*)&Qs[(qt * 64 + w * 16 + l15) * 64 + ((g ^ r7) * 8)];
        qbh[qt][1] = *(const bf16x8*)&Qs[(qt * 64 + w * 16 + l15) * 64 + (((4 + g) ^ r7) * 8)];
    }

    float m_run[2] = {-1e30f, -1e30f}, l_run[2] = {0.f, 0.f};
    f32x4 O[2][4] = {{{0,0,0,0},{0,0,0,0},{0,0,0,0},{0,0,0,0}},
                     {{0,0,0,0},{0,0,0,0},{0,0,0,0},{0,0,0,0}}};

    for (int kt = 0; kt < 512; kt += 64) {
        __syncthreads();
        #pragma unroll
        for (int q = 0; q < 2; ++q) {
            const int rb = w * 16 + q * 8;
            stage8_swz(&Kh_g[((size_t)(b * 512 + kt + rb)) * 1024 + h * 64], 1024,
                       &Ks[rb * 64], lane);
            stage8_swz(&Wh_g[((size_t)(bh * 64 + rb)) * 512 + kt], 512,
                       &Wsh[rb * 64], lane);
        }
        __syncthreads();
        #pragma unroll
        for (int qt = 0; qt < 2; ++qt) {
            f32x4 st[4];
            #pragma unroll
            for (int tk = 0; tk < 4; ++tk) {
                f32x4 a = {0.f, 0.f, 0.f, 0.f};
                #pragma unroll
                for (int c = 0; c < 2; ++c) {
                    bf16x8 kah = *(const bf16x8*)&Ks[(tk * 16 + l15) * 64 + (((c * 4 + g) ^ r7) * 8)];
                    a = MFMA16(kah, qbh[qt][c], a);
                }
                st[tk] = a;
            }
            float mt = st[0][0];
            #pragma unroll
            for (int tk = 0; tk < 4; ++tk)
                #pragma unroll
                for (int r = 0; r < 4; ++r) mt = fmaxf(mt, st[tk][r]);
            mt = fmaxf(mt, __shfl_xor(mt, 16));
            mt = fmaxf(mt, __shfl_xor(mt, 32));
            const float m_new = fmaxf(m_run[qt], mt);
            const float scale = __expf((m_run[qt] - m_new) * 0.125f);
            float rsum = 0.f;
            #pragma unroll
            for (int tk = 0; tk < 4; ++tk) {
                float p0_ = __expf((st[tk][0] - m_new) * 0.125f);
                float p1_ = __expf((st[tk][1] - m_new) * 0.125f);
                float p2_ = __expf((st[tk][2] - m_new) * 0.125f);
                float p3_ = __expf((st[tk][3] - m_new) * 0.125f);
                rsum += p0_ + p1_ + p2_ + p3_;
                uint2 hw;
                hw.x = f2bf_rne(p0_) | (f2bf_rne(p1_) << 16);
                hw.y = f2bf_rne(p2_) | (f2bf_rne(p3_) << 16);
                *(uint2*)&Ph[w][l15 * PSTR + tk * 16 + g * 4] = hw;
            }
            rsum += __shfl_xor(rsum, 16);
            rsum += __shfl_xor(rsum, 32);
            l_run[qt] = l_run[qt] * scale + rsum;
            m_run[qt] = m_new;
            float sc[4];
            #pragma unroll
            for (int r = 0; r < 4; ++r) sc[r] = __shfl(scale, g * 4 + r);
            #pragma unroll
            for (int td = 0; td < 4; ++td)
                #pragma unroll
                for (int r = 0; r < 4; ++r) O[qt][td][r] *= sc[r];
            bf16x8 pah[2];
            pah[0] = *(const bf16x8*)&Ph[w][l15 * PSTR + 8 * g];
            pah[1] = *(const bf16x8*)&Ph[w][l15 * PSTR + 32 + 8 * g];
            #pragma unroll
            for (int td = 0; td < 4; ++td) {
                #pragma unroll
                for (int c = 0; c < 2; ++c) {
                    bf16x8 wbh = *(const bf16x8*)&Wsh[(td * 16 + l15) * 64 + (((c * 4 + g) ^ r7) * 8)];
                    O[qt][td] = MFMA16(pah[c], wbh, O[qt][td]);
                }
            }
        }
    }
    #pragma unroll
    for (int qt = 0; qt < 2; ++qt) {
        const float linv = 1.f / l_run[qt];
        float li[4];
        #pragma unroll
        for (int r = 0; r < 4; ++r) li[r] = __shfl(linv, g * 4 + r);
        #pragma unroll
        for (int td = 0; td < 4; ++td)
            #pragma unroll
            for (int r = 0; r < 4; ++r) {
                const float v = O[qt][td][r] * li[r];
                const size_t idx = ((size_t)(b * 512 + q0 + qt * 64 + w * 16 + g * 4 + r)) * 1024
                                 + h * 64 + td * 16 + l15;
                const u32 hh = f2bf_rne(v);
                attnh[idx] = (u16)hh;
                attnl[idx] = (u16)f2bf_rne(v - bf_lo(hh));
            }
    }
}

// ---------------------------------------------------------------------------
extern "C" void kernel_launch(void* const* d_in, const int* in_sizes, int n_in,
                              void* d_out, int out_size, void* d_ws, size_t ws_size,
                              hipStream_t stream) {
    const float* X  = (const float*)d_in[0];
    const float* Wq = (const float*)d_in[1];
    const float* bq = (const float*)d_in[2];
    const float* Wk = (const float*)d_in[3];
    const float* bk = (const float*)d_in[4];
    const float* Wv = (const float*)d_in[5];
    const float* bv = (const float*)d_in[6];
    const float* Wo = (const float*)d_in[7];
    const float* bo = (const float*)d_in[8];
    float* out = (float*)d_out;

    char* ws = (char*)d_ws;
    size_t off = 0;
    auto alloc = [&](size_t bytes) -> void* {
        void* p = ws + off;
        off += (bytes + 255) & ~(size_t)255;
        return p;
    };
    const size_t NE = (size_t)NR_ * D_;               // 4,194,304
    const size_t HE = (size_t)BH_ * 64 * 512;         // 4,194,304
    u16*   Xh    = (u16*)alloc(NE * 2);
    u16*   WTh   = (u16*)alloc((size_t)4 * 1024 * 1024 * 2);
    u16*   QKh   = (u16*)alloc(2 * NE * 2);           // [Q|K][4096][1024]
    u16*   Kn    = (u16*)alloc(NE * 2);
    u16*   VdT   = (u16*)alloc(HE * 2);
    u16*   WhT   = (u16*)alloc(HE * 2);
    u16*   attnh = (u16*)alloc(NE * 2);
    u16*   attnl = (u16*)alloc(NE * 2);

    const u16* Qh_g = QKh;
    const u16* Kh_g = QKh + NE;

    dim3 blk(256);
    prep_kernel<<<dim3(16, 16, 5), blk, 0, stream>>>(X, Xh, Wq, Wk, Wv, Wo, WTh);
    gemm_mfma<1><<<dim3(64, 24), blk, 0, stream>>>(Xh, nullptr, WTh, bq, bk, bv,
                                                   nullptr, QKh, Kn, VdT, 1);
    qgfd_mfma<<<dim3(4, BH_), blk, 0, stream>>>(Kn, VdT, WhT);
    attn_mfma<<<dim3(4, BH_), blk, 0, stream>>>(Qh_g, Kh_g, WhT, attnh, attnl);
    gemm_mfma<2><<<dim3(64, 8), blk, 0, stream>>>(attnh, attnl,
                                                  WTh + ((size_t)3 << 20),
                                                  bo, bo, bo, out, nullptr,
                                                  nullptr, nullptr, 0);
}